// Round 12
// baseline (148.409 us; speedup 1.0000x reference)
//
#include <hip/hip_runtime.h>
#include <hip/hip_fp16.h>

// NCC loss: 9^3 box sums of {I, J, I*I, J*J, I*J}, per-voxel cc, -mean(cc).
// Dims: C=2, D=192, H=224, W=192, fp32.
// D-FIRST factorization (box sums separable in any order):
//   P1 (k_dprod): K2-shaped pure-stream PRODUCER. Thread owns a (h,w) px-pair,
//     marches D with a 9-deep register ring of the 5 products; writes D-summed
//     fields fp16 (half2). Zero LDS / cross-lane / barriers.
//   P2 (k_hwcc): zero-LDS CONSUMER. Thread owns 4 w-px, marches H with running
//     H-sums (add h+4 prefetched raw, drop h-4 cache-hot reload) over the 5
//     fp16 fields; 9-tap W-window in-thread; cc + block reduce. Writes nothing.
// Rationale: 11 structurally different H/W-first pass-1 kernels all pinned at
// ~3 TB/s; the fast shapes on this machine are K2-like streams (5.9 TB/s) —
// so make both passes that shape and delete the bottleneck kernel.

#define C2   2
#define DDIM 192
#define HDIM 224
#define WDIM 192
#define HWN  (HDIM*WDIM)              // 43008
#define VOL  ((size_t)DDIM*HWN)       // 8257536 (per input channel)
#define SVOL ((size_t)DDIM*HWN)       // per (f,c) field plane
#define RAD  4
#define WINV (1.0f/729.0f)

#define HT2  28   // P2 h-strip (224/28 = 8)

// ---------------- P1: D-direction box sum of the 5 product fields ----------------
// grid: (HWN/512, DDIM/DS, C2); block 256; thread owns px-pair (2*pair, 2*pair+1)
// buf layout (fp16): [f][c][d][h][w]
__global__ __launch_bounds__(256)
void k_dprod(const float* __restrict__ I, const float* __restrict__ J,
             __half* __restrict__ buf, int DS)
{
    const int tid  = threadIdx.x;
    const int pair = blockIdx.x*256 + tid;    // HWN/2 = 21504 pairs
    const int pix  = 2*pair;
    const int c    = blockIdx.z;
    const int ds0  = blockIdx.y*DS;

    const float* Ib = I + (size_t)c*VOL + pix;
    const float* Jb = J + (size_t)c*VOL + pix;

    __half* ob0 = buf + (size_t)(0*C2 + c)*SVOL + pix;
    __half* ob1 = buf + (size_t)(1*C2 + c)*SVOL + pix;
    __half* ob2 = buf + (size_t)(2*C2 + c)*SVOL + pix;
    __half* ob3 = buf + (size_t)(3*C2 + c)*SVOL + pix;
    __half* ob4 = buf + (size_t)(4*C2 + c)*SVOL + pix;

    float2 ring[5][9];
    float2 rs[5];
    #pragma unroll
    for (int f = 0; f < 5; ++f) { rs[f].x = 0.f; rs[f].y = 0.f; }

    // warm-up: slices ds0-4 .. ds0+3 (zero padded)
    #pragma unroll
    for (int k = 0; k < 8; ++k) {
        const int dd = ds0 - RAD + k;
        float2 iv = {0.f,0.f}, jv = {0.f,0.f};
        if ((unsigned)dd < (unsigned)DDIM) {
            iv = *(const float2*)(Ib + (size_t)dd*HWN);
            jv = *(const float2*)(Jb + (size_t)dd*HWN);
        }
        float2 pr[5];
        pr[0] = iv; pr[1] = jv;
        pr[2].x = iv.x*iv.x; pr[2].y = iv.y*iv.y;
        pr[3].x = jv.x*jv.x; pr[3].y = jv.y*jv.y;
        pr[4].x = iv.x*jv.x; pr[4].y = iv.y*jv.y;
        #pragma unroll
        for (int f = 0; f < 5; ++f) {
            ring[f][k] = pr[f];
            rs[f].x += pr[f].x; rs[f].y += pr[f].y;
        }
    }

    int i = 0;
    while (i < DS) {
        #pragma unroll
        for (int p = 0; p < 9; ++p) {   // i == p (mod 9) whenever body runs
            if (i < DS) {
                const int dd = ds0 + i + RAD;    // incoming slice
                float2 iv = {0.f,0.f}, jv = {0.f,0.f};
                if (dd < DDIM) {
                    iv = *(const float2*)(Ib + (size_t)dd*HWN);
                    jv = *(const float2*)(Jb + (size_t)dd*HWN);
                }
                float2 pr[5];
                pr[0] = iv; pr[1] = jv;
                pr[2].x = iv.x*iv.x; pr[2].y = iv.y*iv.y;
                pr[3].x = jv.x*jv.x; pr[3].y = jv.y*jv.y;
                pr[4].x = iv.x*jv.x; pr[4].y = iv.y*jv.y;
                const size_t doff = (size_t)(ds0 + i)*HWN;   // output slice d
                #pragma unroll
                for (int f = 0; f < 5; ++f) {
                    rs[f].x += pr[f].x; rs[f].y += pr[f].y;  // D-sum at d
                    const __half2 h2 = __floats2half2_rn(rs[f].x, rs[f].y);
                    __half* ob = (f==0)?ob0:(f==1)?ob1:(f==2)?ob2:(f==3)?ob3:ob4;
                    *reinterpret_cast<__half2*>(ob + doff) = h2;
                    rs[f].x -= ring[f][p].x; rs[f].y -= ring[f][p].y; // drop d-8
                    ring[f][(p+8)%9] = pr[f];                        // keep dd
                }
                ++i;
            }
        }
    }
}

// ---------------- P2: H-sum + W-window + cc + reduce, zero-LDS ----------------
// grid: (DDIM/4, HDIM/HT2, C2); block 192 = 48 w-groups x 4 d-slices
__global__ __launch_bounds__(192)
void k_hwcc(const __half* __restrict__ buf, double* __restrict__ gacc)
{
    const int tid  = threadIdx.x;
    const int wg   = tid % 48;        // w-group (4 px)
    const int dloc = tid / 48;
    const int w0   = 4*wg;
    const int d    = (int)blockIdx.x*4 + dloc;
    const int h0   = (int)blockIdx.y*HT2;
    const int c    = (int)blockIdx.z;
    const bool le = (wg == 0), re = (wg == 47);

    // per-field row bases (fp16), at column w0
    const __half* B[5];
    #pragma unroll
    for (int f = 0; f < 5; ++f)
        B[f] = buf + (size_t)(f*C2 + c)*SVOL + (size_t)d*HWN + w0;

    // running H-sums: per field, spans L=[w0-4..w0-1] M=[w0..w0+3] R=[w0+4..w0+7]
    float4 L[5], M[5], R[5];
    #pragma unroll
    for (int f = 0; f < 5; ++f) {
        L[f].x=L[f].y=L[f].z=L[f].w=0.f;
        M[f].x=M[f].y=M[f].z=M[f].w=0.f;
        R[f].x=R[f].y=R[f].z=R[f].w=0.f;
    }

    // raw fp16 span loads (uint2 = 4 halfs); masked lanes stay zero
#define LOADRAW(H, OK, A)                                                     \
    {                                                                         \
        _Pragma("unroll")                                                     \
        for (int f = 0; f < 5; ++f) {                                         \
            const __half* rp = B[f] + (size_t)(H)*WDIM;                       \
            A[f][0].x = A[f][0].y = 0u;                                       \
            A[f][1].x = A[f][1].y = 0u;                                       \
            A[f][2].x = A[f][2].y = 0u;                                       \
            if (OK) {                                                         \
                A[f][1] = *reinterpret_cast<const uint2*>(rp);                \
                if (!le) A[f][0] = *reinterpret_cast<const uint2*>(rp - 4);   \
                if (!re) A[f][2] = *reinterpret_cast<const uint2*>(rp + 4);   \
            }                                                                 \
        }                                                                     \
    }

#define CVT4(U, V)                                                            \
    {                                                                         \
        const __half2 h01 = __builtin_bit_cast(__half2, U.x);                 \
        const __half2 h23 = __builtin_bit_cast(__half2, U.y);                 \
        const float2 f01 = __half22float2(h01);                               \
        const float2 f23 = __half22float2(h23);                               \
        V.x = f01.x; V.y = f01.y; V.z = f23.x; V.w = f23.y;                   \
    }

    uint2 pa[5][3], da[5][3];

    // warm-up: rows h0-4 .. h0+3
    for (int k = 0; k < 8; ++k) {
        const int h = h0 - RAD + k;
        LOADRAW(h, (h >= 0), da);
        #pragma unroll
        for (int f = 0; f < 5; ++f) {
            float4 v;
            CVT4(da[f][0], v); L[f].x+=v.x; L[f].y+=v.y; L[f].z+=v.z; L[f].w+=v.w;
            CVT4(da[f][1], v); M[f].x+=v.x; M[f].y+=v.y; M[f].z+=v.z; M[f].w+=v.w;
            CVT4(da[f][2], v); R[f].x+=v.x; R[f].y+=v.y; R[f].z+=v.z; R[f].w+=v.w;
        }
    }
    // prefetch row h0+4 (always < HDIM)
    LOADRAW(h0 + RAD, true, pa);

    float acc = 0.f;

    for (int i = 0; i < HT2; ++i) {
        const int h = h0 + i;
        // add prefetched row h+4
        #pragma unroll
        for (int f = 0; f < 5; ++f) {
            float4 v;
            CVT4(pa[f][0], v); L[f].x+=v.x; L[f].y+=v.y; L[f].z+=v.z; L[f].w+=v.w;
            CVT4(pa[f][1], v); M[f].x+=v.x; M[f].y+=v.y; M[f].z+=v.z; M[f].w+=v.w;
            CVT4(pa[f][2], v); R[f].x+=v.x; R[f].y+=v.y; R[f].z+=v.z; R[f].w+=v.w;
        }
        // prefetch next add row (h+5)
        LOADRAW(h + RAD + 1, (i + 1 < HT2) && (h + RAD + 1 < HDIM), pa);
        // issue drop-row loads (h-4, cache-hot) — consumed after the window
        LOADRAW(h - RAD, (h - RAD >= 0), da);

        // 9-tap W-window per field -> full 3D sums for the 4 px
        float o[5][4];
        #pragma unroll
        for (int f = 0; f < 5; ++f) {
            const float o0 = ((L[f].x+L[f].y)+(L[f].z+L[f].w))
                           + ((M[f].x+M[f].y)+(M[f].z+M[f].w)) + R[f].x;
            o[f][0] = o0;
            o[f][1] = o0      - L[f].x + R[f].y;
            o[f][2] = o[f][1] - L[f].y + R[f].z;
            o[f][3] = o[f][2] - L[f].z + R[f].w;
        }
        #pragma unroll
        for (int j = 0; j < 4; ++j) {
            const float uI    = o[0][j]*WINV;
            const float uJ    = o[1][j]*WINV;
            const float cross = o[4][j] - uJ*o[0][j];
            const float Iv    = o[2][j] - uI*o[0][j];
            const float Jv    = o[3][j] - uJ*o[1][j];
            acc += cross*cross / (Iv*Jv + 1e-5f);
        }

        // drop row h-4
        #pragma unroll
        for (int f = 0; f < 5; ++f) {
            float4 v;
            CVT4(da[f][0], v); L[f].x-=v.x; L[f].y-=v.y; L[f].z-=v.z; L[f].w-=v.w;
            CVT4(da[f][1], v); M[f].x-=v.x; M[f].y-=v.y; M[f].z-=v.z; M[f].w-=v.w;
            CVT4(da[f][2], v); R[f].x-=v.x; R[f].y-=v.y; R[f].z-=v.z; R[f].w-=v.w;
        }
    }
#undef LOADRAW
#undef CVT4

    // block reduction (3 waves) -> one double atomic per block
    __shared__ float wred[3];
    #pragma unroll
    for (int off = 32; off > 0; off >>= 1) acc += __shfl_down(acc, off);
    if ((tid & 63) == 0) wred[tid >> 6] = acc;
    __syncthreads();
    if (tid == 0) {
        const float sum = wred[0] + wred[1] + wred[2];
        atomicAdd(gacc, (double)sum);
    }
}

__global__ void k_fin(const double* __restrict__ gacc, float* __restrict__ out)
{
    out[0] = (float)(-gacc[0] / (double)((size_t)C2*DDIM*HDIM*WDIM));
}

extern "C" void kernel_launch(void* const* d_in, const int* in_sizes, int n_in,
                              void* d_out, int out_size, void* d_ws, size_t ws_size,
                              hipStream_t stream)
{
    if (n_in < 2) return;
    const float* I = (const float*)d_in[0];
    const float* J = (const float*)d_in[1];
    float* out = (float*)d_out;
    double* gacc = (double*)d_ws;
    __half* buf = (__half*)((char*)d_ws + 256);

    // full-volume fp16 D-summed fields: 5*2*192*43008*2 B = 165.2 MB
    const size_t need = 256 + (size_t)5*C2*SVOL*sizeof(__half);
    if (need > ws_size) return;   // ws known to be >= ~179 MB in this harness

    hipMemsetAsync(d_ws, 0, 256, stream);   // zero the double accumulator

    const int DS = 48;                       // 4 D-chunks for parallelism
    dim3 g1(HWN/512, DDIM/DS, C2);           // 84 x 4 x 2 blocks
    k_dprod<<<g1, dim3(256,1,1), 0, stream>>>(I, J, buf, DS);

    dim3 g2(DDIM/4, HDIM/HT2, C2);           // 48 x 8 x 2 blocks
    k_hwcc<<<g2, dim3(192,1,1), 0, stream>>>(buf, gacc);

    k_fin<<<1,1,0,stream>>>(gacc, out);
}